// Round 5
// baseline (650.991 us; speedup 1.0000x reference)
//
#include <hip/hip_runtime.h>

#define S_LEN 512
#define BATCH 256
#define EMB   300
#define HID   256
#define VOCAB 50257
#define NPROD 786                      // ceil(50257/64) producer blocks

typedef __attribute__((ext_vector_type(8))) _Float16 f16x8;
typedef __attribute__((ext_vector_type(4))) _Float16 f16x4;
typedef __attribute__((ext_vector_type(4))) float    f32x4;

// Barrier that waits only lgkmcnt(0): LDS ordering preserved, global loads
// stay in flight across it (vmcnt untouched).
__device__ __forceinline__ void block_sync_lds() {
    asm volatile("" ::: "memory");
    __builtin_amdgcn_s_waitcnt(0xC07F);   // vmcnt=63, expcnt=7, lgkmcnt=0
    __builtin_amdgcn_s_barrier();
    asm volatile("" ::: "memory");
}

__device__ __forceinline__ float sigmoidf_fast(float x) {
    float e = __builtin_amdgcn_exp2f(x * -1.44269504089f);
    return __builtin_amdgcn_rcpf(1.0f + e);
}

// ---------------------------------------------------------------------------
// Producer: EmbWi[v][j] = (emb[v] @ Wi)[j], f32. 786 blocks x 64 rows.
// No LDS: A-fragments loaded directly from emb (lane(ln,q) reads 32 contiguous
// bytes of row m0+mt*16+ln), pipelined one kc ahead. Wi fp16 frags in regs.
// ---------------------------------------------------------------------------
__global__ __launch_bounds__(256, 1)
void k_embwi(const float* __restrict__ emb, const float* __restrict__ Wi,
             float* __restrict__ EW) {
    const int tid  = threadIdx.x;
    const int wv   = tid >> 6;
    const int lane = tid & 63;
    const int ln   = lane & 15;
    const int q    = lane >> 4;
    const int m0   = blockIdx.x * 64;

    // Wi frags: B[k][n], k = kc*32 + q*8 + j, n = wv*64 + nt*16 + ln
    f16x8 bfrag[10][4];
#pragma unroll
    for (int kc = 0; kc < 10; kc++) {
#pragma unroll
        for (int nt = 0; nt < 4; nt++) {
            const int n = wv * 64 + nt * 16 + ln;
            f16x8 u;
#pragma unroll
            for (int j = 0; j < 8; j++) {
                const int k = kc * 32 + q * 8 + j;
                u[j] = (k < EMB) ? (_Float16)Wi[k * HID + n] : (_Float16)0.f;
            }
            bfrag[kc][nt] = u;
        }
    }

    // per-lane emb row pointers (A[m][k]: m = mt*16 + ln, k = kc*32 + q*8 + jj)
    const float* arow[4];
#pragma unroll
    for (int mt = 0; mt < 4; mt++) {
        int row = m0 + mt * 16 + ln; if (row >= VOCAB) row = VOCAB - 1;
        arow[mt] = emb + (long)row * EMB + q * 8;
    }

    auto load_af = [&](int kc, int mt) -> f16x8 {
        const float* p = arow[mt] + kc * 32;
        f16x8 v;
        if (kc < 9 || q == 0) {                 // k0+8 <= 300
            f32x4 a = *(const f32x4*)p;
            f32x4 b = *(const f32x4*)(p + 4);
#pragma unroll
            for (int r = 0; r < 4; r++) { v[r] = (_Float16)a[r]; v[4 + r] = (_Float16)b[r]; }
        } else if (q == 1) {                    // k0=296: 296..299 valid
            f32x4 a = *(const f32x4*)p;
#pragma unroll
            for (int r = 0; r < 4; r++) { v[r] = (_Float16)a[r]; v[4 + r] = (_Float16)0.f; }
        } else {
#pragma unroll
            for (int r = 0; r < 8; r++) v[r] = (_Float16)0.f;
        }
        return v;
    };

    f32x4 acc[4][4];
#pragma unroll
    for (int mt = 0; mt < 4; mt++)
#pragma unroll
        for (int nt = 0; nt < 4; nt++)
            acc[mt][nt] = f32x4{0.f, 0.f, 0.f, 0.f};

    f16x8 af[4], afn[4];
#pragma unroll
    for (int mt = 0; mt < 4; mt++) af[mt] = load_af(0, mt);

#pragma unroll
    for (int kc = 0; kc < 10; kc++) {
        if (kc < 9) {
#pragma unroll
            for (int mt = 0; mt < 4; mt++) afn[mt] = load_af(kc + 1, mt);
        }
#pragma unroll
        for (int mt = 0; mt < 4; mt++)
#pragma unroll
            for (int nt = 0; nt < 4; nt++)
                acc[mt][nt] = __builtin_amdgcn_mfma_f32_16x16x32_f16(
                    af[mt], bfrag[kc][nt], acc[mt][nt], 0, 0, 0);
#pragma unroll
        for (int mt = 0; mt < 4; mt++) af[mt] = afn[mt];
    }

    // C: row = m0 + mt*16 + q*4 + r, col = wv*64 + nt*16 + ln
#pragma unroll
    for (int mt = 0; mt < 4; mt++)
#pragma unroll
        for (int nt = 0; nt < 4; nt++) {
            const int col = wv * 64 + nt * 16 + ln;
#pragma unroll
            for (int r = 0; r < 4; r++) {
                const int mm = m0 + mt * 16 + q * 4 + r;
                if (mm < VOCAB) EW[(long)mm * HID + col] = acc[mt][nt][r];
            }
        }
}

// ---------------------------------------------------------------------------
// Consumer: recurrence. 16 blocks x 16 batch rows, 4 waves split j.
// h ping-pongs in LDS (HSTR=264: balanced b128 reads/writes). a_t gathered
// from EmbWi 2 steps ahead into regs, used directly as MFMA C-init.
// k split into two independent accumulator chains (depth 4) to cover MFMA
// dependent-issue latency (~37 cyc) at 1 wave/SIMD.
// ---------------------------------------------------------------------------
#define HSTR 264
#define HB   (16 * HSTR)
#define WSTR 516   // wtab dword stride: 516%32=4 -> 2-way (free)

__global__ __launch_bounds__(256, 1)
void k_recur(const float* __restrict__ Wh, const float* __restrict__ EW,
             const int* __restrict__ words,
             const float* __restrict__ fcw, const float* __restrict__ fcb,
             float* __restrict__ out) {
    __shared__ __attribute__((aligned(16))) _Float16 hbuf[2 * HB];
    __shared__ int wtab[16 * WSTR];
    __shared__ float red[256];

    const int tid  = threadIdx.x;
    const int wv   = tid >> 6;
    const int lane = tid & 63;
    const int ln   = lane & 15;
    const int q    = lane >> 4;
    const int b0   = blockIdx.x * 16;

    // stage words as prescaled EW byte offsets (row * 256 cols * 4 B = row<<10)
    for (int i = tid; i < 16 * S_LEN; i += 256)
        wtab[(i >> 9) * WSTR + (i & 511)] = words[b0 * S_LEN + i] << 10;

    // Wh^T fragments: A'[m=j][k] = Wh[k][j], j = wv*64 + mt*16 + ln
    f16x8 whf[8][4];
#pragma unroll
    for (int kc = 0; kc < 8; kc++) {
#pragma unroll
        for (int mt = 0; mt < 4; mt++) {
            const int j = wv * 64 + mt * 16 + ln;
            f16x8 u;
#pragma unroll
            for (int jj = 0; jj < 8; jj++)
                u[jj] = (_Float16)Wh[(kc * 32 + q * 8 + jj) * HID + j];
            whf[kc][mt] = u;
        }
    }

    for (int i = tid; i < 2 * HB; i += 256) hbuf[i] = (_Float16)0.f;
    __syncthreads();

    const int jbase = wv * 64 + q * 4;   // + mt*16
    f32x4 abuf0[4], abuf1[4];
    {
        const float* r0 = (const float*)((const char*)EW + wtab[ln * WSTR + 0]) + jbase;
        const float* r1 = (const float*)((const char*)EW + wtab[ln * WSTR + 1]) + jbase;
#pragma unroll
        for (int mt = 0; mt < 4; mt++) abuf0[mt] = *(const f32x4*)(r0 + mt * 16);
#pragma unroll
        for (int mt = 0; mt < 4; mt++) abuf1[mt] = *(const f32x4*)(r1 + mt * 16);
    }

#define STEP(T, ABUF)                                                                   \
    {                                                                                   \
        const int tt = (T);                                                             \
        const _Float16* hr = hbuf + ((tt & 1) ? HB : 0);                                \
        _Float16*       hw = hbuf + ((tt & 1) ? 0 : HB);                                \
        const int t2 = (tt + 2 > 511) ? 511 : (tt + 2);                                 \
        const int wofs = wtab[ln * WSTR + t2];          /* first DS op this step */     \
        f16x8 hf[8];                                                                    \
        _Pragma("unroll")                                                               \
        for (int kc = 0; kc < 8; kc++)                                                  \
            hf[kc] = *(const f16x8*)(hr + ln * HSTR + kc * 32 + q * 8);                 \
        const float* rp = (const float*)((const char*)EW + wofs) + jbase;               \
        f32x4 acc_a[4], acc_b[4];                                                       \
        _Pragma("unroll")                                                               \
        for (int mt = 0; mt < 4; mt++) acc_a[mt] = ABUF[mt];   /* preact C-init */      \
        _Pragma("unroll")                                                               \
        for (int mt = 0; mt < 4; mt++) ABUF[mt] = *(const f32x4*)(rp + mt * 16);        \
        _Pragma("unroll")                                                               \
        for (int mt = 0; mt < 4; mt++) acc_b[mt] = f32x4{0.f, 0.f, 0.f, 0.f};           \
        _Pragma("unroll")                                                               \
        for (int r = 0; r < 4; r++) {      /* 8 independent chains, depth 4 */          \
            _Pragma("unroll")                                                           \
            for (int mt = 0; mt < 4; mt++)                                              \
                acc_a[mt] = __builtin_amdgcn_mfma_f32_16x16x32_f16(                     \
                    whf[r][mt], hf[r], acc_a[mt], 0, 0, 0);                             \
            _Pragma("unroll")                                                           \
            for (int mt = 0; mt < 4; mt++)                                              \
                acc_b[mt] = __builtin_amdgcn_mfma_f32_16x16x32_f16(                     \
                    whf[r + 4][mt], hf[r + 4], acc_b[mt], 0, 0, 0);                     \
        }                                                                               \
        _Pragma("unroll")                                                               \
        for (int mt = 0; mt < 4; mt++) {                                                \
            f32x4 s = acc_a[mt] + acc_b[mt];                                            \
            f16x4 hp;                                                                   \
            _Pragma("unroll")                                                           \
            for (int r = 0; r < 4; r++) hp[r] = (_Float16)sigmoidf_fast(s[r]);          \
            *(f16x4*)(hw + ln * HSTR + wv * 64 + mt * 16 + q * 4) = hp;                 \
        }                                                                               \
        block_sync_lds();                                                               \
    }

    for (int t = 0; t < S_LEN; t += 2) {
        STEP(t, abuf0);
        STEP(t + 1, abuf1);
    }
#undef STEP

    const _Float16* hf0 = hbuf;   // step 511 (odd) wrote buffer 0

    {
        const int row = tid >> 4, j0 = (tid & 15) * 16;
        float* dst = out + 256 + (long)(b0 + row) * HID + j0;
#pragma unroll
        for (int v = 0; v < 16; v += 4) {
            f32x4 w;
#pragma unroll
            for (int r = 0; r < 4; r++) w[r] = (float)hf0[row * HSTR + j0 + v + r];
            *(f32x4*)(dst + v) = w;
        }
    }

    {
        const int bl = tid >> 4, part = tid & 15;
        float s = 0.f;
#pragma unroll
        for (int jj = 0; jj < 16; jj++) {
            const int j = part * 16 + jj;
            s += (float)hf0[bl * HSTR + j] * fcw[j];
        }
        red[bl * 16 + part] = s;
    }
    __syncthreads();
    if (tid < 16) {
        float s = fcb[0];
#pragma unroll
        for (int p = 0; p < 16; p++) s += red[tid * 16 + p];
        out[b0 + tid] = sigmoidf_fast(s);
    }
}

extern "C" void kernel_launch(void* const* d_in, const int* in_sizes, int n_in,
                              void* d_out, int out_size, void* d_ws, size_t ws_size,
                              hipStream_t stream) {
    const int*   words = (const int*)d_in[0];
    const float* emb   = (const float*)d_in[1];
    const float* Wi    = (const float*)d_in[2];
    const float* Wh    = (const float*)d_in[3];
    const float* fcw   = (const float*)d_in[4];
    const float* fcb   = (const float*)d_in[5];
    float* EW   = (float*)d_ws;                       // 51.5 MB, f32
    float* outp = (float*)d_out;

    // same-stream ordering replaces the R4 flag/spin: consumer needs the full
    // EmbWi table anyway, and separate dispatches give clean per-kernel counters.
    hipLaunchKernelGGL(k_embwi, dim3(NPROD), dim3(256), 0, stream, emb, Wi, EW);
    hipLaunchKernelGGL(k_recur, dim3(BATCH / 16), dim3(256), 0, stream,
                       Wh, EW, words, fcw, fcb, outp);
}

// Round 7
// 611.748 us; speedup vs baseline: 1.0641x; 1.0641x over previous
//
#include <hip/hip_runtime.h>

#define S_LEN 512
#define BATCH 256
#define EMB   300
#define HID   256
#define VOCAB 50257
#define NPROD 786                       // ceil(50257/64) producer blocks
#define NLOG2E -1.44269504089f

#define EW_BYTES   51463168ull          // 50257*256*4 (f32, pre-scaled by -log2e)
#define ASEQ_BYTES 67108864ull          // 512*256*256*2 (f16)

typedef __attribute__((ext_vector_type(8))) _Float16 f16x8;
typedef __attribute__((ext_vector_type(4))) _Float16 f16x4;
typedef __attribute__((ext_vector_type(2))) __fp16   fp16v2;  // cvt_pkrtz native type
typedef __attribute__((ext_vector_type(4))) float    f32x4;

// Barrier that waits only lgkmcnt(0): LDS ordering preserved, global loads
// stay in flight across it (vmcnt untouched).
__device__ __forceinline__ void block_sync_lds() {
    asm volatile("" ::: "memory");
    __builtin_amdgcn_s_waitcnt(0xC07F);   // vmcnt=63, expcnt=7, lgkmcnt=0
    __builtin_amdgcn_s_barrier();
    asm volatile("" ::: "memory");
}

// x_s = -log2e * x  (scale pre-folded into the weights) -> sigma = 1/(1+2^x_s)
__device__ __forceinline__ float sigmoid_scaled(float xs) {
    float e = __builtin_amdgcn_exp2f(xs);
    return __builtin_amdgcn_rcpf(1.0f + e);
}

// ---------------------------------------------------------------------------
// Producer: EW[v][j] = -log2e * (emb[v] @ Wi)[j], f32. 786 blocks x 64 rows.
// ---------------------------------------------------------------------------
__global__ __launch_bounds__(256, 1)
void k_embwi(const float* __restrict__ emb, const float* __restrict__ Wi,
             float* __restrict__ EW) {
    const int tid  = threadIdx.x;
    const int wv   = tid >> 6;
    const int lane = tid & 63;
    const int ln   = lane & 15;
    const int q    = lane >> 4;
    const int m0   = blockIdx.x * 64;

    // Wi frags (scaled by -log2e): B[k][n], k = kc*32 + q*8 + j, n = wv*64 + nt*16 + ln
    f16x8 bfrag[10][4];
#pragma unroll
    for (int kc = 0; kc < 10; kc++) {
#pragma unroll
        for (int nt = 0; nt < 4; nt++) {
            const int n = wv * 64 + nt * 16 + ln;
            f16x8 u;
#pragma unroll
            for (int j = 0; j < 8; j++) {
                const int k = kc * 32 + q * 8 + j;
                u[j] = (k < EMB) ? (_Float16)(Wi[k * HID + n] * NLOG2E) : (_Float16)0.f;
            }
            bfrag[kc][nt] = u;
        }
    }

    const float* arow[4];
#pragma unroll
    for (int mt = 0; mt < 4; mt++) {
        int row = m0 + mt * 16 + ln; if (row >= VOCAB) row = VOCAB - 1;
        arow[mt] = emb + (long)row * EMB + q * 8;
    }

    auto load_af = [&](int kc, int mt) -> f16x8 {
        const float* p = arow[mt] + kc * 32;
        f16x8 v;
        if (kc < 9 || q == 0) {
            f32x4 a = *(const f32x4*)p;
            f32x4 b = *(const f32x4*)(p + 4);
#pragma unroll
            for (int r = 0; r < 4; r++) { v[r] = (_Float16)a[r]; v[4 + r] = (_Float16)b[r]; }
        } else if (q == 1) {
            f32x4 a = *(const f32x4*)p;
#pragma unroll
            for (int r = 0; r < 4; r++) { v[r] = (_Float16)a[r]; v[4 + r] = (_Float16)0.f; }
        } else {
#pragma unroll
            for (int r = 0; r < 8; r++) v[r] = (_Float16)0.f;
        }
        return v;
    };

    f32x4 acc[4][4];
#pragma unroll
    for (int mt = 0; mt < 4; mt++)
#pragma unroll
        for (int nt = 0; nt < 4; nt++)
            acc[mt][nt] = f32x4{0.f, 0.f, 0.f, 0.f};

    f16x8 af[4], afn[4];
#pragma unroll
    for (int mt = 0; mt < 4; mt++) af[mt] = load_af(0, mt);

#pragma unroll
    for (int kc = 0; kc < 10; kc++) {
        if (kc < 9) {
#pragma unroll
            for (int mt = 0; mt < 4; mt++) afn[mt] = load_af(kc + 1, mt);
        }
#pragma unroll
        for (int mt = 0; mt < 4; mt++)
#pragma unroll
            for (int nt = 0; nt < 4; nt++)
                acc[mt][nt] = __builtin_amdgcn_mfma_f32_16x16x32_f16(
                    af[mt], bfrag[kc][nt], acc[mt][nt], 0, 0, 0);
#pragma unroll
        for (int mt = 0; mt < 4; mt++) af[mt] = afn[mt];
    }

#pragma unroll
    for (int mt = 0; mt < 4; mt++)
#pragma unroll
        for (int nt = 0; nt < 4; nt++) {
            const int col = wv * 64 + nt * 16 + ln;
#pragma unroll
            for (int r = 0; r < 4; r++) {
                const int mm = m0 + mt * 16 + q * 4 + r;
                if (mm < VOCAB) EW[(long)mm * HID + col] = acc[mt][nt][r];
            }
        }
}

// ---------------------------------------------------------------------------
// Expand: A_seq[t][b][j] = (f16) EW[words[b,t]][j].  Turns the per-step gather
// into a one-shot full-GPU pass; consumer then streams sequentially.
// 8 elems/thread; 32 threads cover one 1KB row (coalesced read + write).
// ---------------------------------------------------------------------------
__global__ __launch_bounds__(256)
void k_expand(const int* __restrict__ words, const float* __restrict__ EW,
              _Float16* __restrict__ As) {
    const int g  = blockIdx.x * 256 + threadIdx.x;   // 0 .. 4194303
    const int e0 = g << 3;
    const int t  = e0 >> 16;
    const int b  = (e0 >> 8) & 255;
    const int j0 = e0 & 255;
    const float* src = EW + ((long)words[b * S_LEN + t] << 8) + j0;
    f32x4 a = *(const f32x4*)src;
    f32x4 c = *(const f32x4*)(src + 4);
    f16x8 v;
#pragma unroll
    for (int r = 0; r < 4; r++) { v[r] = (_Float16)a[r]; v[4 + r] = (_Float16)c[r]; }
    *(f16x8*)(As + e0) = v;
}

// ---------------------------------------------------------------------------
// Consumer (stream): 16 blocks x 16 batch rows, 4 waves split j.
// Sequential pre-scaled f16 A_seq feed (R2-proven), register prefetch depth 2.
// Dual independent MFMA accumulator chains (depth 4) for issue-latency cover.
// ---------------------------------------------------------------------------
#define HSTR 264
#define HB   (16 * HSTR)

__global__ __launch_bounds__(256, 1)
void k_recur_s(const float* __restrict__ Wh, const _Float16* __restrict__ As,
               const float* __restrict__ fcw, const float* __restrict__ fcb,
               float* __restrict__ out) {
    __shared__ __attribute__((aligned(16))) _Float16 hbuf[2 * HB];
    __shared__ float red[256];

    const int tid  = threadIdx.x;
    const int wv   = tid >> 6;
    const int lane = tid & 63;
    const int ln   = lane & 15;
    const int q    = lane >> 4;
    const int b0   = blockIdx.x * 16;

    // Wh^T frags (scaled by -log2e): A'[m=j][k] = Wh[k][j], j = wv*64 + mt*16 + ln
    f16x8 whf[8][4];
#pragma unroll
    for (int kc = 0; kc < 8; kc++) {
#pragma unroll
        for (int mt = 0; mt < 4; mt++) {
            const int j = wv * 64 + mt * 16 + ln;
            f16x8 u;
#pragma unroll
            for (int jj = 0; jj < 8; jj++)
                u[jj] = (_Float16)(Wh[(kc * 32 + q * 8 + jj) * HID + j] * NLOG2E);
            whf[kc][mt] = u;
        }
    }

    for (int i = tid; i < 2 * HB; i += 256) hbuf[i] = (_Float16)0.f;
    __syncthreads();

    const int jbase = wv * 64 + q * 4;   // + mt*16
    const _Float16* abase = As + (long)(b0 + ln) * HID + jbase;
    f16x4 abuf0[4], abuf1[4];
#pragma unroll
    for (int mt = 0; mt < 4; mt++) abuf0[mt] = *(const f16x4*)(abase + 0L * 65536 + mt * 16);
#pragma unroll
    for (int mt = 0; mt < 4; mt++) abuf1[mt] = *(const f16x4*)(abase + 1L * 65536 + mt * 16);

#define STEP(T, ABUF)                                                                   \
    {                                                                                   \
        const int tt = (T);                                                             \
        const _Float16* hr = hbuf + ((tt & 1) ? HB : 0);                                \
        _Float16*       hw = hbuf + ((tt & 1) ? 0 : HB);                                \
        f16x8 hf[8];                                                                    \
        _Pragma("unroll")                                                               \
        for (int kc = 0; kc < 8; kc++)                                                  \
            hf[kc] = *(const f16x8*)(hr + ln * HSTR + kc * 32 + q * 8);                 \
        f32x4 acc_a[4], acc_b[4];                                                       \
        _Pragma("unroll")                                                               \
        for (int mt = 0; mt < 4; mt++) {            /* preact (f16->f32) as C-init */   \
            f16x4 av = ABUF[mt];                                                        \
            acc_a[mt] = f32x4{(float)av[0], (float)av[1], (float)av[2], (float)av[3]};  \
            acc_b[mt] = f32x4{0.f, 0.f, 0.f, 0.f};                                      \
        }                                                                               \
        const long t2 = (tt + 2 > 511) ? 511 : (tt + 2);                                \
        const _Float16* rp = abase + t2 * 65536;                                        \
        _Pragma("unroll")                                                               \
        for (int mt = 0; mt < 4; mt++) ABUF[mt] = *(const f16x4*)(rp + mt * 16);        \
        _Pragma("unroll")                                                               \
        for (int r = 0; r < 4; r++) {               /* 8 chains, depth 4 */             \
            _Pragma("unroll")                                                           \
            for (int mt = 0; mt < 4; mt++)                                              \
                acc_a[mt] = __builtin_amdgcn_mfma_f32_16x16x32_f16(                     \
                    whf[r][mt], hf[r], acc_a[mt], 0, 0, 0);                             \
            _Pragma("unroll")                                                           \
            for (int mt = 0; mt < 4; mt++)                                              \
                acc_b[mt] = __builtin_amdgcn_mfma_f32_16x16x32_f16(                     \
                    whf[r + 4][mt], hf[r + 4], acc_b[mt], 0, 0, 0);                     \
        }                                                                               \
        _Pragma("unroll")                                                               \
        for (int mt = 0; mt < 4; mt++) {                                                \
            f32x4 s = acc_a[mt] + acc_b[mt];                                            \
            float r0 = sigmoid_scaled(s[0]), r1 = sigmoid_scaled(s[1]);                 \
            float r2 = sigmoid_scaled(s[2]), r3 = sigmoid_scaled(s[3]);                 \
            union { fp16v2 h2[2]; f16x4 v4; } hp;                                       \
            hp.h2[0] = __builtin_amdgcn_cvt_pkrtz(r0, r1);                              \
            hp.h2[1] = __builtin_amdgcn_cvt_pkrtz(r2, r3);                              \
            *(f16x4*)(hw + ln * HSTR + wv * 64 + mt * 16 + q * 4) = hp.v4;              \
        }                                                                               \
        block_sync_lds();                                                               \
    }

    for (int t = 0; t < S_LEN; t += 2) {
        STEP(t, abuf0);
        STEP(t + 1, abuf1);
    }
#undef STEP

    const _Float16* hf0 = hbuf;   // step 511 (odd) wrote buffer 0

    {
        const int row = tid >> 4, j0 = (tid & 15) * 16;
        float* dst = out + 256 + (long)(b0 + row) * HID + j0;
#pragma unroll
        for (int v = 0; v < 16; v += 4) {
            f32x4 w;
#pragma unroll
            for (int r = 0; r < 4; r++) w[r] = (float)hf0[row * HSTR + j0 + v + r];
            *(f32x4*)(dst + v) = w;
        }
    }

    {
        const int bl = tid >> 4, part = tid & 15;
        float s = 0.f;
#pragma unroll
        for (int jj = 0; jj < 16; jj++) {
            const int j = part * 16 + jj;
            s += (float)hf0[bl * HSTR + j] * fcw[j];
        }
        red[bl * 16 + part] = s;
    }
    __syncthreads();
    if (tid < 16) {
        float s = fcb[0];
#pragma unroll
        for (int p = 0; p < 16; p++) s += red[tid * 16 + p];
        s *= NLOG2E;                       // fc path is unscaled -> scale here
        out[b0 + tid] = sigmoid_scaled(s);
    }
}

// ---------------------------------------------------------------------------
// Consumer (gather fallback, R5 structure): used only if ws is too small.
// ---------------------------------------------------------------------------
#define WSTR 516

__global__ __launch_bounds__(256, 1)
void k_recur_g(const float* __restrict__ Wh, const float* __restrict__ EW,
               const int* __restrict__ words,
               const float* __restrict__ fcw, const float* __restrict__ fcb,
               float* __restrict__ out) {
    __shared__ __attribute__((aligned(16))) _Float16 hbuf[2 * HB];
    __shared__ int wtab[16 * WSTR];
    __shared__ float red[256];

    const int tid  = threadIdx.x;
    const int wv   = tid >> 6;
    const int lane = tid & 63;
    const int ln   = lane & 15;
    const int q    = lane >> 4;
    const int b0   = blockIdx.x * 16;

    for (int i = tid; i < 16 * S_LEN; i += 256)
        wtab[(i >> 9) * WSTR + (i & 511)] = words[b0 * S_LEN + i] << 10;

    f16x8 whf[8][4];
#pragma unroll
    for (int kc = 0; kc < 8; kc++) {
#pragma unroll
        for (int mt = 0; mt < 4; mt++) {
            const int j = wv * 64 + mt * 16 + ln;
            f16x8 u;
#pragma unroll
            for (int jj = 0; jj < 8; jj++)
                u[jj] = (_Float16)(Wh[(kc * 32 + q * 8 + jj) * HID + j] * NLOG2E);
            whf[kc][mt] = u;
        }
    }

    for (int i = tid; i < 2 * HB; i += 256) hbuf[i] = (_Float16)0.f;
    __syncthreads();

    const int jbase = wv * 64 + q * 4;
    f32x4 abuf0[4], abuf1[4];
    {
        const float* r0 = (const float*)((const char*)EW + wtab[ln * WSTR + 0]) + jbase;
        const float* r1 = (const float*)((const char*)EW + wtab[ln * WSTR + 1]) + jbase;
#pragma unroll
        for (int mt = 0; mt < 4; mt++) abuf0[mt] = *(const f32x4*)(r0 + mt * 16);
#pragma unroll
        for (int mt = 0; mt < 4; mt++) abuf1[mt] = *(const f32x4*)(r1 + mt * 16);
    }

#define STEP(T, ABUF)                                                                   \
    {                                                                                   \
        const int tt = (T);                                                             \
        const _Float16* hr = hbuf + ((tt & 1) ? HB : 0);                                \
        _Float16*       hw = hbuf + ((tt & 1) ? 0 : HB);                                \
        const int t2 = (tt + 2 > 511) ? 511 : (tt + 2);                                 \
        const int wofs = wtab[ln * WSTR + t2];                                          \
        f16x8 hf[8];                                                                    \
        _Pragma("unroll")                                                               \
        for (int kc = 0; kc < 8; kc++)                                                  \
            hf[kc] = *(const f16x8*)(hr + ln * HSTR + kc * 32 + q * 8);                 \
        const float* rp = (const float*)((const char*)EW + wofs) + jbase;               \
        f32x4 acc_a[4], acc_b[4];                                                       \
        _Pragma("unroll")                                                               \
        for (int mt = 0; mt < 4; mt++) { acc_a[mt] = ABUF[mt];                          \
                                         acc_b[mt] = f32x4{0.f, 0.f, 0.f, 0.f}; }      \
        _Pragma("unroll")                                                               \
        for (int mt = 0; mt < 4; mt++) ABUF[mt] = *(const f32x4*)(rp + mt * 16);        \
        _Pragma("unroll")                                                               \
        for (int r = 0; r < 4; r++) {                                                   \
            _Pragma("unroll")                                                           \
            for (int mt = 0; mt < 4; mt++)                                              \
                acc_a[mt] = __builtin_amdgcn_mfma_f32_16x16x32_f16(                     \
                    whf[r][mt], hf[r], acc_a[mt], 0, 0, 0);                             \
            _Pragma("unroll")                                                           \
            for (int mt = 0; mt < 4; mt++)                                              \
                acc_b[mt] = __builtin_amdgcn_mfma_f32_16x16x32_f16(                     \
                    whf[r + 4][mt], hf[r + 4], acc_b[mt], 0, 0, 0);                     \
        }                                                                               \
        _Pragma("unroll")                                                               \
        for (int mt = 0; mt < 4; mt++) {                                                \
            f32x4 s = acc_a[mt] + acc_b[mt];                                            \
            float r0 = sigmoid_scaled(s[0]), r1 = sigmoid_scaled(s[1]);                 \
            float r2 = sigmoid_scaled(s[2]), r3 = sigmoid_scaled(s[3]);                 \
            union { fp16v2 h2[2]; f16x4 v4; } hp;                                       \
            hp.h2[0] = __builtin_amdgcn_cvt_pkrtz(r0, r1);                              \
            hp.h2[1] = __builtin_amdgcn_cvt_pkrtz(r2, r3);                              \
            *(f16x4*)(hw + ln * HSTR + wv * 64 + mt * 16 + q * 4) = hp.v4;              \
        }                                                                               \
        block_sync_lds();                                                               \
    }

    for (int t = 0; t < S_LEN; t += 2) {
        STEP(t, abuf0);
        STEP(t + 1, abuf1);
    }
#undef STEP

    const _Float16* hf0 = hbuf;
    {
        const int row = tid >> 4, j0 = (tid & 15) * 16;
        float* dst = out + 256 + (long)(b0 + row) * HID + j0;
#pragma unroll
        for (int v = 0; v < 16; v += 4) {
            f32x4 w;
#pragma unroll
            for (int r = 0; r < 4; r++) w[r] = (float)hf0[row * HSTR + j0 + v + r];
            *(f32x4*)(dst + v) = w;
        }
    }
    {
        const int bl = tid >> 4, part = tid & 15;
        float s = 0.f;
#pragma unroll
        for (int jj = 0; jj < 16; jj++)
            s += (float)hf0[bl * HSTR + part * 16 + jj] * fcw[part * 16 + jj];
        red[bl * 16 + part] = s;
    }
    __syncthreads();
    if (tid < 16) {
        float s = fcb[0];
#pragma unroll
        for (int p = 0; p < 16; p++) s += red[tid * 16 + p];
        s *= NLOG2E;
        out[b0 + tid] = sigmoid_scaled(s);
    }
}

extern "C" void kernel_launch(void* const* d_in, const int* in_sizes, int n_in,
                              void* d_out, int out_size, void* d_ws, size_t ws_size,
                              hipStream_t stream) {
    const int*   words = (const int*)d_in[0];
    const float* emb   = (const float*)d_in[1];
    const float* Wi    = (const float*)d_in[2];
    const float* Wh    = (const float*)d_in[3];
    const float* fcw   = (const float*)d_in[4];
    const float* fcb   = (const float*)d_in[5];
    float*    EW   = (float*)d_ws;
    _Float16* As   = (_Float16*)((char*)d_ws + EW_BYTES);
    float*    outp = (float*)d_out;

    hipLaunchKernelGGL(k_embwi, dim3(NPROD), dim3(256), 0, stream, emb, Wi, EW);
    if (ws_size >= EW_BYTES + ASEQ_BYTES) {
        hipLaunchKernelGGL(k_expand, dim3(16384), dim3(256), 0, stream, words, EW, As);
        hipLaunchKernelGGL(k_recur_s, dim3(BATCH / 16), dim3(256), 0, stream,
                           Wh, As, fcw, fcb, outp);
    } else {
        hipLaunchKernelGGL(k_recur_g, dim3(BATCH / 16), dim3(256), 0, stream,
                           Wh, EW, words, fcw, fcb, outp);
    }
}